// Round 1
// baseline (2728.520 us; speedup 1.0000x reference)
//
#include <hip/hip_runtime.h>

#define GRID_RES 64
#define NPTS 1048576
#define CH 64
#define IMG 512

__global__ __launch_bounds__(256) void gs_tok(
    const int* __restrict__ coords,
    const float* __restrict__ feat,
    const float* __restrict__ Km,
    const float* __restrict__ Pm,
    float* __restrict__ out_feat,
    float* __restrict__ out_depth)
{
    int t = blockIdx.x * blockDim.x + threadIdx.x;
    int point = t >> 6;      // one wave (64 lanes) == one point
    int c = t & 63;          // lane == channel
    if (point >= NPTS) return;

    const int4 cd = ((const int4*)coords)[point];
    int b = cd.x;
    const float s = 2.0f / (GRID_RES - 1);
    float wx = (float)cd.y * s - 1.0f;
    float wy = (float)cd.z * s - 1.0f;
    float wz = (float)cd.w * s - 1.0f;

    // cam = P @ [wx,wy,wz,1]
    float cx = Pm[0]*wx  + Pm[1]*wy  + Pm[2]*wz  + Pm[3];
    float cy = Pm[4]*wx  + Pm[5]*wy  + Pm[6]*wz  + Pm[7];
    float cz = Pm[8]*wx  + Pm[9]*wy  + Pm[10]*wz + Pm[11];
    float cw = Pm[12]*wx + Pm[13]*wy + Pm[14]*wz + Pm[15];
    cx = cx / cw; cy = cy / cw; cz = cz / cw;   // cam /= cam.w

    // img_h = K @ cam.xyz
    float ix = Km[0]*cx + Km[1]*cy + Km[2]*cz;
    float iy = Km[3]*cx + Km[4]*cy + Km[5]*cz;
    float iz = Km[6]*cx + Km[7]*cy + Km[8]*cz;
    float x = ix / iz;
    float y = iy / iz;

    float fi = floorf(y);
    float fj = floorf(x);
    float di = y - fi;
    float dj = x - fj;

    int i0 = min(max((int)fi, 0), IMG - 1);
    int i1 = min(max((int)fi + 1, 0), IMG - 1);
    int j0 = min(max((int)fj, 0), IMG - 1);
    int j1 = min(max((int)fj + 1, 0), IMG - 1);

    // feature plane for (batch b, channel c): 512*512 = 1<<18 floats
    const float* base = feat + ((size_t)(b * CH + c) << 18);
    const float* r0 = base + (i0 << 9);
    const float* r1 = base + (i1 << 9);
    float f00 = r0[j0];
    float f01 = r0[j1];
    float f10 = r1[j0];
    float f11 = r1[j1];

    float omdi = 1.0f - di;
    float mj  = omdi * f00 + di * f10;
    float mjp = omdi * f01 + di * f11;
    float res = (1.0f - dj) * mj + dj * mjp;

    out_feat[(size_t)point * CH + c] = res;
    if (c == 0) out_depth[point] = cz;
}

extern "C" void kernel_launch(void* const* d_in, const int* in_sizes, int n_in,
                              void* d_out, int out_size, void* d_ws, size_t ws_size,
                              hipStream_t stream)
{
    const int*   coords = (const int*)d_in[0];
    const float* feat   = (const float*)d_in[1];
    const float* Km     = (const float*)d_in[2];
    const float* Pm     = (const float*)d_in[3];
    float* out_feat  = (float*)d_out;
    float* out_depth = (float*)d_out + (size_t)NPTS * CH;

    const int threads = 256;
    const long long total = (long long)NPTS * 64;
    const int blocks = (int)((total + threads - 1) / threads);
    gs_tok<<<blocks, threads, 0, stream>>>(coords, feat, Km, Pm, out_feat, out_depth);
}

// Round 2
// 1422.666 us; speedup vs baseline: 1.9179x; 1.9179x over previous
//
#include <hip/hip_runtime.h>
#include <stdint.h>

#define GRID_RES 64
#define NPTS 1048576
#define CH 64
#define IMG 512
#define NBINS 1024              // 4 batches x 16 x 16 tiles of 32x32 px
#define NBLK_D (NPTS / 4)       // gather: 4 points (waves) per 256-thr block
#define CHUNKS_PER_XCD (NBLK_D / 8)

struct Rec { float di, dj; uint32_t meta, pt; };

__device__ __forceinline__ void project_point(
    const int4 cd, const float* __restrict__ Km, const float* __restrict__ Pm,
    float& di, float& dj, int& i0, int& i1, int& j0, int& j1, int& b, float& cz_out)
{
    b = cd.x;
    const float s = 2.0f / (GRID_RES - 1);
    float wx = (float)cd.y * s - 1.0f;
    float wy = (float)cd.z * s - 1.0f;
    float wz = (float)cd.w * s - 1.0f;

    float cx = Pm[0]*wx  + Pm[1]*wy  + Pm[2]*wz  + Pm[3];
    float cy = Pm[4]*wx  + Pm[5]*wy  + Pm[6]*wz  + Pm[7];
    float cz = Pm[8]*wx  + Pm[9]*wy  + Pm[10]*wz + Pm[11];
    float cw = Pm[12]*wx + Pm[13]*wy + Pm[14]*wz + Pm[15];
    cx = cx / cw; cy = cy / cw; cz = cz / cw;

    float ix = Km[0]*cx + Km[1]*cy + Km[2]*cz;
    float iy = Km[3]*cx + Km[4]*cy + Km[5]*cz;
    float iz = Km[6]*cx + Km[7]*cy + Km[8]*cz;
    float x = ix / iz;
    float y = iy / iz;

    float fi = floorf(y);
    float fj = floorf(x);
    di = y - fi;
    dj = x - fj;
    i0 = min(max((int)fi, 0), IMG - 1);
    i1 = min(max((int)fi + 1, 0), IMG - 1);
    j0 = min(max((int)fj, 0), IMG - 1);
    j1 = min(max((int)fj + 1, 0), IMG - 1);
    cz_out = cz;
}

// ---- Pass 0: zero bin counters -------------------------------------------
__global__ void pass_zero(uint32_t* counts) {
    counts[threadIdx.x] = 0;   // 1 block x 1024 threads
}

// ---- Pass A: project, write depth + per-point record, histogram bins -----
__global__ __launch_bounds__(256) void pass_hist(
    const int* __restrict__ coords, const float* __restrict__ Km,
    const float* __restrict__ Pm, uint32_t* __restrict__ counts,
    Rec* __restrict__ tmp, float* __restrict__ out_depth)
{
    __shared__ uint32_t h[NBINS];
    for (int i = threadIdx.x; i < NBINS; i += 256) h[i] = 0;
    __syncthreads();

    int pt = blockIdx.x * 256 + threadIdx.x;
    const int4 cd = ((const int4*)coords)[pt];
    float di, dj, cz; int i0, i1, j0, j1, b;
    project_point(cd, Km, Pm, di, dj, i0, i1, j0, j1, b, cz);

    Rec r;
    r.di = di; r.dj = dj;
    r.meta = ((uint32_t)b << 20) | ((uint32_t)i0 << 11) | ((uint32_t)j0 << 2)
           | ((uint32_t)(i1 - i0) << 1) | (uint32_t)(j1 - j0);
    r.pt = (uint32_t)pt;
    tmp[pt] = r;
    out_depth[pt] = cz;

    int bin = (b << 8) | ((i0 >> 5) << 4) | (j0 >> 5);
    atomicAdd(&h[bin], 1u);
    __syncthreads();
    for (int i = threadIdx.x; i < NBINS; i += 256)
        if (h[i]) atomicAdd(&counts[i], h[i]);
}

// ---- Pass B: exclusive scan of 1024 bin counts → cursor ------------------
__global__ void pass_scan(const uint32_t* __restrict__ counts, uint32_t* __restrict__ cursor) {
    __shared__ uint32_t a[NBINS];
    int t = threadIdx.x;            // 1 block x 1024 threads
    a[t] = counts[t];
    __syncthreads();
    for (int off = 1; off < NBINS; off <<= 1) {
        uint32_t v = a[t];
        uint32_t add = (t >= off) ? a[t - off] : 0u;
        __syncthreads();
        a[t] = v + add;
        __syncthreads();
    }
    cursor[t] = (t == 0) ? 0u : a[t - 1];
}

// ---- Pass C: scatter records into bin-sorted order -----------------------
__global__ __launch_bounds__(256) void pass_scatter(
    const Rec* __restrict__ tmp, uint32_t* __restrict__ cursor, Rec* __restrict__ recs)
{
    int pt = blockIdx.x * 256 + threadIdx.x;
    Rec r = tmp[pt];
    int i0 = (r.meta >> 11) & 511;
    int j0 = (r.meta >> 2) & 511;
    int b  = r.meta >> 20;
    int bin = (b << 8) | ((i0 >> 5) << 4) | (j0 >> 5);
    uint32_t pos = atomicAdd(&cursor[bin], 1u);
    recs[pos] = r;
}

// ---- Pass D: gather — one wave per point, lane = channel -----------------
__global__ __launch_bounds__(256) void pass_gather(
    const Rec* __restrict__ recs, const float* __restrict__ feat,
    float* __restrict__ out_feat)
{
    uint32_t bi = blockIdx.x;
    // XCD-affinity swizzle: XCD (= bi % 8) sweeps a contiguous 1/8 of the
    // sorted array so each screen tile's lines live in exactly one L2.
    uint32_t chunk = (bi & 7u) * CHUNKS_PER_XCD + (bi >> 3);
    uint32_t p = chunk * 4u + (threadIdx.x >> 6);
    int c = threadIdx.x & 63;

    Rec r = recs[p];                       // same addr across wave → broadcast
    int j1d = r.meta & 1;
    int i1d = (r.meta >> 1) & 1;
    int j0  = (r.meta >> 2) & 511;
    int i0  = (r.meta >> 11) & 511;
    int b   = r.meta >> 20;

    const float* base = feat + ((size_t)(b * CH + c) << 18);
    const float* r0 = base + (i0 << 9);
    const float* r1 = r0 + (i1d << 9);
    float f00 = r0[j0];
    float f01 = r0[j0 + j1d];
    float f10 = r1[j0];
    float f11 = r1[j0 + j1d];

    float omdi = 1.0f - r.di;
    float mj  = omdi * f00 + r.di * f10;
    float mjp = omdi * f01 + r.di * f11;
    float res = (1.0f - r.dj) * mj + r.dj * mjp;

    out_feat[(size_t)r.pt * CH + c] = res;
}

// ---- Fallback: round-1 kernel (used only if ws too small) ----------------
__global__ __launch_bounds__(256) void gs_tok(
    const int* __restrict__ coords, const float* __restrict__ feat,
    const float* __restrict__ Km, const float* __restrict__ Pm,
    float* __restrict__ out_feat, float* __restrict__ out_depth)
{
    int t = blockIdx.x * blockDim.x + threadIdx.x;
    int point = t >> 6;
    int c = t & 63;
    if (point >= NPTS) return;
    const int4 cd = ((const int4*)coords)[point];
    float di, dj, cz; int i0, i1, j0, j1, b;
    project_point(cd, Km, Pm, di, dj, i0, i1, j0, j1, b, cz);
    const float* base = feat + ((size_t)(b * CH + c) << 18);
    const float* r0 = base + (i0 << 9);
    const float* r1 = base + (i1 << 9);
    float f00 = r0[j0], f01 = r0[j1], f10 = r1[j0], f11 = r1[j1];
    float omdi = 1.0f - di;
    float mj  = omdi * f00 + di * f10;
    float mjp = omdi * f01 + di * f11;
    float res = (1.0f - dj) * mj + dj * mjp;
    out_feat[(size_t)point * CH + c] = res;
    if (c == 0) out_depth[point] = cz;
}

extern "C" void kernel_launch(void* const* d_in, const int* in_sizes, int n_in,
                              void* d_out, int out_size, void* d_ws, size_t ws_size,
                              hipStream_t stream)
{
    const int*   coords = (const int*)d_in[0];
    const float* feat   = (const float*)d_in[1];
    const float* Km     = (const float*)d_in[2];
    const float* Pm     = (const float*)d_in[3];
    float* out_feat  = (float*)d_out;
    float* out_depth = (float*)d_out + (size_t)NPTS * CH;

    const size_t counts_off = 0;
    const size_t cursor_off = 4096;
    const size_t tmp_off    = 16384;
    const size_t recs_off   = 16384 + (size_t)NPTS * sizeof(Rec);
    const size_t need       = recs_off + (size_t)NPTS * sizeof(Rec);

    if (ws_size < need) {
        // Fallback: unbinned single pass
        const long long total = (long long)NPTS * 64;
        gs_tok<<<(int)((total + 255) / 256), 256, 0, stream>>>(
            coords, feat, Km, Pm, out_feat, out_depth);
        return;
    }

    uint32_t* counts = (uint32_t*)((char*)d_ws + counts_off);
    uint32_t* cursor = (uint32_t*)((char*)d_ws + cursor_off);
    Rec*      tmp    = (Rec*)((char*)d_ws + tmp_off);
    Rec*      recs   = (Rec*)((char*)d_ws + recs_off);

    pass_zero<<<1, NBINS, 0, stream>>>(counts);
    pass_hist<<<NPTS / 256, 256, 0, stream>>>(coords, Km, Pm, counts, tmp, out_depth);
    pass_scan<<<1, NBINS, 0, stream>>>(counts, cursor);
    pass_scatter<<<NPTS / 256, 256, 0, stream>>>(tmp, cursor, recs);
    pass_gather<<<NBLK_D, 256, 0, stream>>>(recs, feat, out_feat);
}